// Round 1
// baseline (11411.382 us; speedup 1.0000x reference)
//
#include <hip/hip_runtime.h>

typedef unsigned short u16;
typedef unsigned int u32;
typedef __attribute__((ext_vector_type(4))) float f32x4;
typedef __attribute__((ext_vector_type(8))) short s16x8;

#define B_ 64
#define T_ 512
#define E_ 1024
#define H_ 1024
#define HE_ 2048
#define N4_ 4096   // 4*H

__device__ __forceinline__ u16 f32_bf16(float f) {
  union { float f; u32 u; } v; v.f = f;
  u32 r = v.u + 0x7FFFu + ((v.u >> 16) & 1u);
  return (u16)(r >> 16);
}
__device__ __forceinline__ float bf16_f32(u16 h) {
  union { u32 u; float f; } v; v.u = ((u32)h) << 16;
  return v.f;
}
__device__ __forceinline__ void async16(void* lds, const void* g) {
  __builtin_amdgcn_global_load_lds(
      (const __attribute__((address_space(1))) void*)g,
      (__attribute__((address_space(3))) void*)lds, 16, 0, 0);
}
__device__ __forceinline__ float sigmoidf_(float x) {
  return 1.0f / (1.0f + __expf(-x));
}

// ---------------- fp32 -> bf16 bulk convert (4 elems/thread) ----------------
__global__ __launch_bounds__(256) void cvt4(const float* __restrict__ s,
                                            u16* __restrict__ d, int n4) {
  int i = blockIdx.x * 256 + threadIdx.x;
  if (i < n4) {
    float4 v = ((const float4*)s)[i];
    u16 o0 = f32_bf16(v.x), o1 = f32_bf16(v.y), o2 = f32_bf16(v.z), o3 = f32_bf16(v.w);
    ushort4 o; o.x = o0; o.y = o1; o.z = o2; o.w = o3;
    ((ushort4*)d)[i] = o;
  }
}

// ---------------- init: a0->bf16, c0 copy, bias concat ----------------
__global__ __launch_bounds__(256) void init_k(const float* __restrict__ a0,
                                              const float* __restrict__ c0,
                                              const float* __restrict__ bc,
                                              const float* __restrict__ bu,
                                              const float* __restrict__ bf_,
                                              const float* __restrict__ bo,
                                              u16* __restrict__ abuf0,
                                              float* __restrict__ c_ws,
                                              float* __restrict__ bias4) {
  int i = blockIdx.x * 256 + threadIdx.x;   // 65536 threads
  abuf0[i] = f32_bf16(a0[i]);
  c_ws[i] = c0[i];
  if (i < N4_) {
    int g = i >> 10, h = i & 1023;
    const float* bp = (g == 0) ? bc : (g == 1) ? bu : (g == 2) ? bf_ : bo;
    bias4[i] = bp[h];
  }
}

// ---------------- phase 1: P[t][b][n] = bf16( X @ WxT + bias ) ----------------
// C[M=32768, N=4096] = Xbf[M,1024] @ Wbf[n][1024 + k]  (B^T layout), BM=BN=128, BK=64
__global__ __launch_bounds__(256) void gemm_p1(const u16* __restrict__ Xbf,
                                               const u16* __restrict__ Wbf,
                                               const float* __restrict__ bias4,
                                               u16* __restrict__ P) {
  __shared__ __align__(16) u16 As[128 * 64];
  __shared__ __align__(16) u16 Bs[128 * 64];
  int tid = threadIdx.x;
  int wid = tid >> 6, lane = tid & 63;
  int lane15 = lane & 15, quad = lane >> 4;
  int m0 = blockIdx.y * 128, n0 = blockIdx.x * 128;
  int wm = (wid >> 1) * 64, wn = (wid & 1) * 64;

  f32x4 acc[4][4] = {};

  for (int kc = 0; kc < 1024; kc += 64) {
    __syncthreads();
    // 32 chunks of 1KB; wave handles 8
    for (int i = 0; i < 8; ++i) {
      int c = wid * 8 + i;
      int o = c * 1024 + lane * 16;          // flat byte offset (As ++ Bs)
      int e = (o & 16383) >> 1;
      int row = e >> 6, kcol = e & 63;
      if (o < 16384) {
        async16((char*)As + c * 1024,
                Xbf + (size_t)(m0 + row) * 1024 + kc + kcol);
      } else {
        async16((char*)Bs + (c - 16) * 1024,
                Wbf + (size_t)(n0 + row) * 2048 + 1024 + kc + kcol);
      }
    }
    __syncthreads();
    for (int s = 0; s < 2; ++s) {
      s16x8 bfrag[4], afrag[4];
      for (int ni = 0; ni < 4; ++ni)
        bfrag[ni] = *(const s16x8*)&Bs[(wn + ni * 16 + lane15) * 64 + s * 32 + quad * 8];
      for (int mi = 0; mi < 4; ++mi)
        afrag[mi] = *(const s16x8*)&As[(wm + mi * 16 + lane15) * 64 + s * 32 + quad * 8];
      for (int mi = 0; mi < 4; ++mi)
        for (int ni = 0; ni < 4; ++ni)
          acc[mi][ni] = __builtin_amdgcn_mfma_f32_16x16x32_bf16(
              afrag[mi], bfrag[ni], acc[mi][ni], 0, 0, 0);
    }
  }
  // epilogue: +bias, write bf16 P at [t][b][n];  m = b*512 + t
  for (int mi = 0; mi < 4; ++mi) {
    int mbase = m0 + wm + mi * 16 + quad * 4;
    for (int ni = 0; ni < 4; ++ni) {
      int n = n0 + wn + ni * 16 + lane15;
      float bv = bias4[n];
      for (int r = 0; r < 4; ++r) {
        int m = mbase + r;
        int b = m >> 9, t = m & 511;
        float v = acc[mi][ni][r] + bv;
        P[(size_t)(t * 64 + b) * N4_ + n] = f32_bf16(v);
      }
    }
  }
}

// ---------------- phase 2: one timestep ----------------
// R[64, 4096] = a_prev @ WaT + P[t]; gates; c,a update.
// grid 64 WGs (h-tile of 16), 4 waves = 4 gates, K=1024 in chunks of 128.
__global__ __launch_bounds__(256) void step_k(const u16* __restrict__ Wbf,
                                              const u16* __restrict__ P,
                                              const u16* __restrict__ a_prev,
                                              u16* __restrict__ a_next,
                                              float* __restrict__ c_ws,
                                              float* __restrict__ a_out,
                                              int t) {
  __shared__ __align__(16) char smem[49152];
  u16* As = (u16*)smem;                  // [64][128] bf16, 16KB
  u16* Bs = (u16*)(smem + 16384);        // [4][16][128] bf16, 16KB
  float* act = (float*)(smem + 32768);   // [64][4][16] f32, 16KB
  u16* Pl = (u16*)smem;                  // reuse As region after K-loop: [64][4][16]

  int tid = threadIdx.x;
  int g = tid >> 6, lane = tid & 63;
  int lane15 = lane & 15, quad = lane >> 4;
  int h0 = blockIdx.x * 16;

  f32x4 acc[4] = {};

  for (int kc = 0; kc < 1024; kc += 128) {
    __syncthreads();
    for (int i = 0; i < 8; ++i) {
      int c = g * 8 + i;
      int o = c * 1024 + lane * 16;
      if (o < 16384) {
        int e = o >> 1;
        int row = e >> 7, kcol = e & 127;
        async16((char*)As + c * 1024,
                a_prev + (size_t)row * 1024 + kc + kcol);
      } else {
        int e = (o - 16384) >> 1;
        int gg = e >> 11;
        int rem = e & 2047;
        int nl = rem >> 7, kcol = rem & 127;
        async16((char*)Bs + (c - 16) * 1024,
                Wbf + (size_t)(gg * 1024 + h0 + nl) * 2048 + kc + kcol);
      }
    }
    __syncthreads();
    for (int s = 0; s < 4; ++s) {
      s16x8 bfrag = *(const s16x8*)&Bs[(g * 16 + lane15) * 128 + s * 32 + quad * 8];
      for (int mi = 0; mi < 4; ++mi) {
        s16x8 afrag = *(const s16x8*)&As[(mi * 16 + lane15) * 128 + s * 32 + quad * 8];
        acc[mi] = __builtin_amdgcn_mfma_f32_16x16x32_bf16(afrag, bfrag, acc[mi], 0, 0, 0);
      }
    }
  }
  __syncthreads();   // done reading As; reuse as Pl
  // load P tile [64 b][4 g][16 h] bf16 (8KB) cooperatively
  for (int j = 0; j < 2; ++j) {
    int idx = tid * 2 + j;                 // [0,512)
    int b = idx >> 3, r = idx & 7, gg = r >> 1, half = r & 1;
    const uint4* src = (const uint4*)(P + (size_t)(t * 64 + b) * N4_ + gg * 1024 + h0 + half * 8);
    ((uint4*)Pl)[idx] = *src;
  }
  __syncthreads();
  // add P, activation, stash in act LDS
  for (int mi = 0; mi < 4; ++mi) {
    for (int r = 0; r < 4; ++r) {
      int b = mi * 16 + quad * 4 + r;
      float p = bf16_f32(Pl[(b * 4 + g) * 16 + lane15]);
      float v = acc[mi][r] + p;
      v = (g == 0) ? tanhf(v) : sigmoidf_(v);
      act[(b * 4 + g) * 16 + lane15] = v;
    }
  }
  __syncthreads();
  // elementwise state update
  for (int j = 0; j < 4; ++j) {
    int e = tid + j * 256;                 // [0,1024) = b*16 + hh
    int b = e >> 4, hh = e & 15;
    float cand = act[(b * 4 + 0) * 16 + hh];
    float u    = act[(b * 4 + 1) * 16 + hh];
    float f    = act[(b * 4 + 2) * 16 + hh];
    float o    = act[(b * 4 + 3) * 16 + hh];
    int ci = b * 1024 + h0 + hh;
    float c1 = u * cand + f * c_ws[ci];
    c_ws[ci] = c1;
    float a1 = o * tanhf(c1);
    a_out[((size_t)b * T_ + t) * H_ + h0 + hh] = a1;
    a_next[ci] = f32_bf16(a1);
  }
}

// ---------------- finalize: a_T, c_T ----------------
__global__ __launch_bounds__(256) void fin_k(const float* __restrict__ a_f,
                                             const float* __restrict__ c_ws,
                                             float* __restrict__ out_aT,
                                             float* __restrict__ out_cT) {
  int i = blockIdx.x * 256 + threadIdx.x;  // 65536
  int b = i >> 10, h = i & 1023;
  out_aT[i] = a_f[((size_t)b * T_ + (T_ - 1)) * H_ + h];
  out_cT[i] = c_ws[i];
}

extern "C" void kernel_launch(void* const* d_in, const int* in_sizes, int n_in,
                              void* d_out, int out_size, void* d_ws, size_t ws_size,
                              hipStream_t stream) {
  const float* x_i = (const float*)d_in[0];
  const float* a0  = (const float*)d_in[1];
  const float* c0  = (const float*)d_in[2];
  const float* w[4] = {(const float*)d_in[3], (const float*)d_in[4],
                       (const float*)d_in[5], (const float*)d_in[6]};
  const float* bb[4] = {(const float*)d_in[7], (const float*)d_in[8],
                        (const float*)d_in[9], (const float*)d_in[10]};
  float* out = (float*)d_out;

  char* ws = (char*)d_ws;
  u16* Wbf   = (u16*)ws;                          // 4*1024*2048*2 = 16,777,216 B
  u16* Xbf   = (u16*)(ws + 16777216);             // 32768*1024*2  = 67,108,864 B
  u16* P     = (u16*)(ws + 83886080);             // 512*64*4096*2 = 268,435,456 B
  float* bias4 = (float*)(ws + 352321536);        // 16,384 B
  u16* abuf0 = (u16*)(ws + 352337920);            // 131,072 B
  u16* abuf1 = (u16*)(ws + 352468992);            // 131,072 B
  float* c_ws = (float*)(ws + 352600064);         // 262,144 B

  // convert weights (keep [n][k] = B^T layout), gates concatenated
  for (int g = 0; g < 4; ++g)
    cvt4<<<2048, 256, 0, stream>>>(w[g], Wbf + (size_t)g * 1024 * 2048, 524288);
  // convert x
  cvt4<<<32768, 256, 0, stream>>>(x_i, Xbf, 8388608);
  // init small state
  init_k<<<256, 256, 0, stream>>>(a0, c0, bb[0], bb[1], bb[2], bb[3],
                                  abuf0, c_ws, bias4);
  // phase 1 big GEMM
  gemm_p1<<<dim3(32, 256), 256, 0, stream>>>(Xbf, Wbf, bias4, P);
  // phase 2: sequential scan
  u16* bufs[2] = {abuf0, abuf1};
  for (int t = 0; t < T_; ++t)
    step_k<<<64, 256, 0, stream>>>(Wbf, P, bufs[t & 1], bufs[(t + 1) & 1],
                                   c_ws, out, t);
  // finalize a_T, c_T
  fin_k<<<256, 256, 0, stream>>>(out, c_ws, out + 33554432, out + 33619968);
}